// Round 7
// baseline (47.653 us; speedup 1.0000x reference)
//
#include <hip/hip_runtime.h>

// out[b,s,d] = relu(x[b,s] * W[s,d] + bias[s,d])
// B=256, S=512, D=512 (fp32). Write-bandwidth kernel: 268 MB out.
//
// Round history:
//   r1/r3/r4 grid-stride resident (8MB smeared window): ~50 us, 5.4 TB/s
//   r2 nontemporal stores: 65 us (regress)
//   r5 per-wave contiguous, full-footprint instantaneous: 60 us (regress)
//   r6 block churn, 16KB chunks, 16384 blocks: 43.5 us, 6.2 TB/s  <- win
// Mechanism: in-order block dispatch + block retirement keeps a dense
// sliding write window. This round: tighten further — 8KB chunks,
// 32768 blocks (2 iters x 4KB per 256-thread block).

typedef float __attribute__((ext_vector_type(4))) floatx4;

__global__ void __launch_bounds__(256) od2d_kernel(
    const float*   __restrict__ x,    // [B*S]
    const floatx4* __restrict__ W4,   // [S*128]
    const floatx4* __restrict__ b4,   // [S*128]
    floatx4*       __restrict__ o4)   // [B*S*128]
{
    const unsigned tid = threadIdx.x;
    const unsigned d4  = tid & 127;
    unsigned i = blockIdx.x * 512 + tid;    // block chunk: 512 float4 = 8 KB

    #pragma unroll
    for (int k = 0; k < 2; ++k) {
        const unsigned bs = i >> 7;
        const unsigned wi = ((bs & 511) << 7) + d4;
        const float xv = x[bs];                 // wave-uniform broadcast
        const floatx4 w  = W4[wi];              // L1/L2-resident
        const floatx4 bb = b4[wi];
        floatx4 r;
        r.x = fmaxf(fmaf(xv, w.x, bb.x), 0.0f);
        r.y = fmaxf(fmaf(xv, w.y, bb.y), 0.0f);
        r.z = fmaxf(fmaf(xv, w.z, bb.z), 0.0f);
        r.w = fmaxf(fmaf(xv, w.w, bb.w), 0.0f);
        o4[i] = r;
        i += 256;                               // next 4 KB slice
    }
}

extern "C" void kernel_launch(void* const* d_in, const int* in_sizes, int n_in,
                              void* d_out, int out_size, void* d_ws, size_t ws_size,
                              hipStream_t stream) {
    const float*   x  = (const float*)d_in[0];
    const floatx4* W4 = (const floatx4*)d_in[1];
    const floatx4* b4 = (const floatx4*)d_in[2];
    floatx4* o4 = (floatx4*)d_out;

    od2d_kernel<<<32768, 256, 0, stream>>>(x, W4, b4, o4);
}

// Round 8
// 44.410 us; speedup vs baseline: 1.0730x; 1.0730x over previous
//
#include <hip/hip_runtime.h>

// out[b,s,d] = relu(x[b,s] * W[s,d] + bias[s,d])
// B=256, S=512, D=512 (fp32). Write-bandwidth kernel: 268 MB out.
//
// Round history:
//   r1/r3/r4 grid-stride resident: ~50 us, 5.4 TB/s
//   r2 nontemporal stores: 65 us (regress)
//   r5 per-wave contiguous scattered: 60 us (regress)
//   r6 block churn 16KB chunks (16384 blocks): 43.5 us, 6.2 TB/s  <- best
//   r7 block churn  8KB chunks (32768 blocks): 47.7 us (dispatch overhead)
// Mechanism: in-order block dispatch keeps a dense sliding write window.
// This round: bracket the chunk-size curve from above — 32KB chunks,
// 8192 blocks x 256 threads x 8 iters (4KB per iter).

typedef float __attribute__((ext_vector_type(4))) floatx4;

__global__ void __launch_bounds__(256) od2d_kernel(
    const float*   __restrict__ x,    // [B*S]
    const floatx4* __restrict__ W4,   // [S*128]
    const floatx4* __restrict__ b4,   // [S*128]
    floatx4*       __restrict__ o4)   // [B*S*128]
{
    const unsigned tid = threadIdx.x;
    const unsigned d4  = tid & 127;
    unsigned i = blockIdx.x * 2048 + tid;   // block chunk: 2048 float4 = 32 KB

    #pragma unroll
    for (int k = 0; k < 8; ++k) {
        const unsigned bs = i >> 7;
        const unsigned wi = ((bs & 511) << 7) + d4;
        const float xv = x[bs];                 // wave-uniform broadcast
        const floatx4 w  = W4[wi];              // L1/L2-resident
        const floatx4 bb = b4[wi];
        floatx4 r;
        r.x = fmaxf(fmaf(xv, w.x, bb.x), 0.0f);
        r.y = fmaxf(fmaf(xv, w.y, bb.y), 0.0f);
        r.z = fmaxf(fmaf(xv, w.z, bb.z), 0.0f);
        r.w = fmaxf(fmaf(xv, w.w, bb.w), 0.0f);
        o4[i] = r;
        i += 256;                               // next 4 KB slice
    }
}

extern "C" void kernel_launch(void* const* d_in, const int* in_sizes, int n_in,
                              void* d_out, int out_size, void* d_ws, size_t ws_size,
                              hipStream_t stream) {
    const float*   x  = (const float*)d_in[0];
    const floatx4* W4 = (const floatx4*)d_in[1];
    const floatx4* b4 = (const floatx4*)d_in[2];
    floatx4* o4 = (floatx4*)d_out;

    od2d_kernel<<<8192, 256, 0, stream>>>(x, W4, b4, o4);
}

// Round 9
// 43.437 us; speedup vs baseline: 1.0971x; 1.0224x over previous
//
#include <hip/hip_runtime.h>

// out[b,s,d] = relu(x[b,s] * W[s,d] + bias[s,d])
// B=256, S=512, D=512 (fp32). Write-bandwidth kernel: 268 MB out.
//
// Round history:
//   r1/r3/r4 grid-stride resident: ~50 us, 5.4 TB/s
//   r2 nontemporal stores: 65 us (regress)
//   r5 per-wave contiguous scattered: 60 us (regress)
//   r6 block churn 16KB chunks (16384 blocks x 4 iters): 43.5 us  <- best
//   r7 block churn  8KB chunks: 47.7 us (dispatch/prologue overhead)
//   r8 block churn 32KB chunks: 44.4 us (window drift)
// Mechanism: in-order block dispatch keeps a dense sliding write window;
// 16KB chunk is the optimum. This round: same 16KB churn, but PREFETCH all
// 12 loads (4x x, W, bias) before the store burst — removes any per-iteration
// load->store vmcnt bubble from the store stream. If neutral: roofline.

typedef float __attribute__((ext_vector_type(4))) floatx4;

__global__ void __launch_bounds__(256) od2d_kernel(
    const float*   __restrict__ x,    // [B*S]
    const floatx4* __restrict__ W4,   // [S*128]
    const floatx4* __restrict__ b4,   // [S*128]
    floatx4*       __restrict__ o4)   // [B*S*128]
{
    const unsigned tid = threadIdx.x;
    const unsigned d4  = tid & 127;
    const unsigned i0  = blockIdx.x * 1024 + tid;  // 16 KB chunk base

    float   xv[4];
    floatx4 w[4], bb[4];
    #pragma unroll
    for (int k = 0; k < 4; ++k) {
        const unsigned ii = i0 + 256u * k;
        const unsigned bs = ii >> 7;
        const unsigned wi = ((bs & 511) << 7) + d4;
        xv[k] = x[bs];          // wave-uniform broadcast
        w[k]  = W4[wi];         // L1/L2-resident
        bb[k] = b4[wi];
    }

    #pragma unroll
    for (int k = 0; k < 4; ++k) {
        floatx4 r;
        r.x = fmaxf(fmaf(xv[k], w[k].x, bb[k].x), 0.0f);
        r.y = fmaxf(fmaf(xv[k], w[k].y, bb[k].y), 0.0f);
        r.z = fmaxf(fmaf(xv[k], w[k].z, bb[k].z), 0.0f);
        r.w = fmaxf(fmaf(xv[k], w[k].w, bb[k].w), 0.0f);
        o4[i0 + 256u * k] = r;
    }
}

extern "C" void kernel_launch(void* const* d_in, const int* in_sizes, int n_in,
                              void* d_out, int out_size, void* d_ws, size_t ws_size,
                              hipStream_t stream) {
    const float*   x  = (const float*)d_in[0];
    const floatx4* W4 = (const floatx4*)d_in[1];
    const floatx4* b4 = (const floatx4*)d_in[2];
    floatx4* o4 = (floatx4*)d_out;

    od2d_kernel<<<16384, 256, 0, stream>>>(x, W4, b4, o4);
}